// Round 5
// baseline (341.271 us; speedup 1.0000x reference)
//
#include <hip/hip_runtime.h>
#include <hip/hip_fp16.h>
#include <math.h>

// 2-layer GAT. N=50000, E=800000 (+N self loops), F=128, H=8, C=32, NCLS=16.
// R5: CSR build rewritten WITHOUT global atomics (theory: 1.7M cross-XCD
// device-scope atomicAdds in k_hist/k_scatter were ~half the runtime).
// Block-partial histograms + LDS atomics + deterministic placement:
//   k_hist2 (64 blocks, 2 half-range LDS passes) -> partial[64][50000]
//   k_scanA (thread/bin: block-prefix in place + deg)
//   k_scan1/2/3 (rowptr, unchanged 2-level scan; cursor+memset dropped)
//   k_scatter2 (LDS cursors = rowptr + block prefix; LDS atomicAdd only)

#define NB   64
#define HALF 25000
#define NBINS 50000

typedef _Float16 f16x8 __attribute__((ext_vector_type(8)));
typedef _Float16 f16x4 __attribute__((ext_vector_type(4)));
typedef float    f32x4 __attribute__((ext_vector_type(4)));

__device__ __forceinline__ float lrelu(float v){ return v > 0.f ? v : 0.2f*v; }

// ---------------- weight prep ----------------
__global__ void k_wprep(const float* __restrict__ W1, _Float16* __restrict__ W1t,
                        const float* __restrict__ W2, _Float16* __restrict__ W2t){
  int b = blockIdx.x, t = threadIdx.x;
  if (b < 128){
    W1t[t*128 + b] = (_Float16)W1[b*256 + t];
  } else {
    for (int i=t; i<4096; i+=256){ int k=i&255, j=i>>8; W2t[j*256+k] = (_Float16)W2[k*16+j]; }
  }
}

// ---------------- CSR build (no global atomics) ----------------
__global__ __launch_bounds__(256) void k_hist2(const int* __restrict__ dstv,
    int* __restrict__ partial, int E, int Etot, int chunk)
{
  __shared__ int cnt[HALF];
  int b = blockIdx.x, t = threadIdx.x;
  int e0 = b*chunk, e1 = e0+chunk; if (e1 > Etot) e1 = Etot;
  for (int half=0; half<2; ++half){
    int lo = half*HALF;
    for (int i=t; i<HALF; i+=256) cnt[i] = 0;
    __syncthreads();
    for (int e=e0+t; e<e1; e+=256){
      int d = (e<E) ? dstv[e] : (e-E);
      int r = d - lo;
      if (r>=0 && r<HALF) atomicAdd(&cnt[r], 1);
    }
    __syncthreads();
    int* dp = partial + (size_t)b*NBINS + lo;
    for (int i=t; i<HALF; i+=256) dp[i] = cnt[i];
    __syncthreads();
  }
}

__global__ void k_scanA(int* __restrict__ partial, int* __restrict__ deg, int Nbins){
  int bin = blockIdx.x*blockDim.x + threadIdx.x;
  if (bin >= Nbins) return;
  int run = 0;
  #pragma unroll 4
  for (int b=0; b<NB; ++b){
    size_t idx = (size_t)b*NBINS + bin;
    int v = partial[idx];
    partial[idx] = run;
    run += v;
  }
  deg[bin] = run;
}

__global__ __launch_bounds__(256) void k_scan1(const int* __restrict__ deg,
    int* __restrict__ rowptr, int* __restrict__ bsum, int N)
{
  __shared__ int lds[256];
  int t = threadIdx.x;
  int base = blockIdx.x*1024 + t*4;
  int v0 = (base+0<N)?deg[base+0]:0;
  int v1 = (base+1<N)?deg[base+1]:0;
  int v2 = (base+2<N)?deg[base+2]:0;
  int v3 = (base+3<N)?deg[base+3]:0;
  int tot = v0+v1+v2+v3;
  lds[t]=tot; __syncthreads();
  for (int off=1; off<256; off<<=1){
    int add = (t>=off)?lds[t-off]:0;
    __syncthreads();
    lds[t] += add;
    __syncthreads();
  }
  int excl = lds[t] - tot;
  if (t==255) bsum[blockIdx.x] = lds[t];
  int run = excl;
  if (base+0<N){ rowptr[base+0]=run; run+=v0; }
  if (base+1<N){ rowptr[base+1]=run; run+=v1; }
  if (base+2<N){ rowptr[base+2]=run; run+=v2; }
  if (base+3<N){ rowptr[base+3]=run; }
}

__global__ __launch_bounds__(256) void k_scan2(int* bsum, int B){
  __shared__ int lds[256];
  int t = threadIdx.x;
  int o = (t<B)?bsum[t]:0;
  lds[t] = o; __syncthreads();
  for (int off=1; off<256; off<<=1){
    int add = (t>=off)?lds[t-off]:0;
    __syncthreads();
    lds[t]+=add;
    __syncthreads();
  }
  if (t<B) bsum[t] = lds[t]-o;
}

__global__ void k_scan3(int* __restrict__ rowptr, const int* __restrict__ bsum, int N, int Etot){
  int i = blockIdx.x*blockDim.x + threadIdx.x;
  if (i < N){
    rowptr[i] += bsum[i>>10];
  } else if (i == N) {
    rowptr[N] = Etot;
  }
}

__global__ __launch_bounds__(256) void k_scatter2(const int* __restrict__ srcv,
    const int* __restrict__ dstv, const int* __restrict__ rowptr,
    const int* __restrict__ partial, int* __restrict__ csr_src, int E, int Etot, int chunk)
{
  __shared__ int cur[HALF];
  int b = blockIdx.x, t = threadIdx.x;
  int e0 = b*chunk, e1 = e0+chunk; if (e1 > Etot) e1 = Etot;
  for (int half=0; half<2; ++half){
    int lo = half*HALF;
    const int* pp = partial + (size_t)b*NBINS + lo;
    const int* rp = rowptr + lo;
    for (int i=t; i<HALF; i+=256) cur[i] = rp[i] + pp[i];
    __syncthreads();
    for (int e=e0+t; e<e1; e+=256){
      int s, d;
      if (e<E){ s=srcv[e]; d=dstv[e]; } else { s=e-E; d=s; }
      int r = d - lo;
      if (r>=0 && r<HALF){
        int pos = atomicAdd(&cur[r], 1);
        csr_src[pos] = s;
      }
    }
    __syncthreads();
  }
}

// ---------------- GEMM1 (MFMA): h1 = x @ W1 -> fp16 [N,256], + a_src1/a_dst1 ----------------
__global__ __launch_bounds__(256) void k_gemm1(const float* __restrict__ x,
    const _Float16* __restrict__ W1t, const float* __restrict__ as1,
    const float* __restrict__ ad1, _Float16* __restrict__ h1,
    float* __restrict__ a_src1, float* __restrict__ a_dst1, int N)
{
  __shared__ char smem[33792];
  _Float16* As = (_Float16*)smem;           // [64 rows][136 halves] (272 B stride)
  int t = threadIdx.x;
  int n0 = blockIdx.x*64;

  #pragma unroll
  for (int it=0; it<8; ++it){
    int c = it*256 + t;
    int row = c >> 5;
    int c4  = c & 31;
    int gr = n0 + row; if (gr > N-1) gr = N-1;
    float4 v = *(const float4*)(x + (size_t)gr*128 + c4*4);
    _Float16* dp = As + row*136 + c4*4;
    dp[0]=(_Float16)v.x; dp[1]=(_Float16)v.y; dp[2]=(_Float16)v.z; dp[3]=(_Float16)v.w;
  }
  __syncthreads();

  int wv = t>>6, lane = t&63;
  int m = lane&15, q = lane>>4;
  int r0w = wv*16;

  f16x8 afr[4];
  #pragma unroll
  for (int ks=0; ks<4; ++ks)
    afr[ks] = *(const f16x8*)((const char*)As + (r0w+m)*272 + ks*64 + q*16);

  f32x4 acc[16];
  #pragma unroll
  for (int ct=0; ct<16; ++ct) acc[ct] = (f32x4){0.f,0.f,0.f,0.f};

  const char* bbase = (const char*)W1t;
  #pragma unroll
  for (int ct=0; ct<16; ++ct){
    const char* bp = bbase + (ct*16 + m)*256 + q*16;
    f16x8 b0 = *(const f16x8*)(bp);
    f16x8 b1 = *(const f16x8*)(bp+64);
    f16x8 b2 = *(const f16x8*)(bp+128);
    f16x8 b3 = *(const f16x8*)(bp+192);
    acc[ct] = __builtin_amdgcn_mfma_f32_16x16x32_f16(afr[0], b0, acc[ct],0,0,0);
    acc[ct] = __builtin_amdgcn_mfma_f32_16x16x32_f16(afr[1], b1, acc[ct],0,0,0);
    acc[ct] = __builtin_amdgcn_mfma_f32_16x16x32_f16(afr[2], b2, acc[ct],0,0,0);
    acc[ct] = __builtin_amdgcn_mfma_f32_16x16x32_f16(afr[3], b3, acc[ct],0,0,0);
  }
  __syncthreads();

  _Float16* Hs = (_Float16*)smem;           // [64][264] halves, 528B stride
  #pragma unroll
  for (int ct=0; ct<16; ++ct){
    #pragma unroll
    for (int r=0; r<4; ++r)
      Hs[(size_t)(r0w + q*4 + r)*264 + ct*16 + m] = (_Float16)acc[ct][r];
  }
  __syncthreads();

  for (int r=0; r<16; ++r){
    int grow = n0 + r0w + r;
    if (grow < N){
      uint2 v = *(const uint2*)((const char*)Hs + (size_t)(r0w+r)*528 + lane*8);
      *(uint2*)((char*)h1 + (size_t)grow*512 + lane*8) = v;
    }
  }

  #pragma unroll
  for (int p=t; p<512; p+=256){
    int row = p>>3, hd = p&7;
    int grow = n0 + row;
    if (grow < N){
      const _Float16* hr = Hs + (size_t)row*264 + hd*32;
      float sa=0.f, sd=0.f;
      #pragma unroll
      for (int c=0; c<32; ++c){
        float hv = (float)hr[c];
        sa += hv * as1[hd*32+c];
        sd += hv * ad1[hd*32+c];
      }
      a_src1[(size_t)grow*8+hd] = sa;
      a_dst1[(size_t)grow*8+hd] = sd;
    }
  }
}

// ---------------- Layer-1 aggregation: wave per dst node, x8/x4/x1 unrolled ----------------
__global__ __launch_bounds__(256) void k_agg1(const __half* __restrict__ h1,
    const float* __restrict__ a_src1, const float* __restrict__ a_dst1,
    const int* __restrict__ rowptr, const int* __restrict__ csr_src,
    const float* __restrict__ bias1, _Float16* __restrict__ h2f, int N)
{
  int wave = (blockIdx.x*blockDim.x + threadIdx.x) >> 6;
  if (wave >= N) return;
  int lane = threadIdx.x & 63;
  int head = lane >> 3;
  float ad = a_dst1[(size_t)wave*8 + head];
  int beg = rowptr[wave], end = rowptr[wave+1];
  float4 acc = make_float4(0.f,0.f,0.f,0.f);
  float wsum = 0.f;
  int i = beg;
  for (; i+8 <= end; i+=8){
    int s[8]; float e[8]; uint2 p[8];
    #pragma unroll
    for (int j=0;j<8;++j) s[j]=csr_src[i+j];
    #pragma unroll
    for (int j=0;j<8;++j){
      e[j]=a_src1[(size_t)s[j]*8+head];
      p[j]=*(const uint2*)((const char*)h1 + (size_t)s[j]*512 + lane*8);
    }
    #pragma unroll
    for (int j=0;j<8;++j){
      float w=__expf(lrelu(e[j]+ad));
      wsum += w;
      const __half2* qq=(const __half2*)&p[j];
      float2 f0=__half22float2(qq[0]), f1=__half22float2(qq[1]);
      acc.x += w*f0.x; acc.y += w*f0.y; acc.z += w*f1.x; acc.w += w*f1.y;
    }
  }
  for (; i+4 <= end; i+=4){
    int s[4]; float e[4]; uint2 p[4];
    #pragma unroll
    for (int j=0;j<4;++j) s[j]=csr_src[i+j];
    #pragma unroll
    for (int j=0;j<4;++j){
      e[j]=a_src1[(size_t)s[j]*8+head];
      p[j]=*(const uint2*)((const char*)h1 + (size_t)s[j]*512 + lane*8);
    }
    #pragma unroll
    for (int j=0;j<4;++j){
      float w=__expf(lrelu(e[j]+ad));
      wsum += w;
      const __half2* qq=(const __half2*)&p[j];
      float2 f0=__half22float2(qq[0]), f1=__half22float2(qq[1]);
      acc.x += w*f0.x; acc.y += w*f0.y; acc.z += w*f1.x; acc.w += w*f1.y;
    }
  }
  for (; i<end; ++i){
    int s = csr_src[i];
    float w = __expf(lrelu(a_src1[(size_t)s*8+head] + ad));
    wsum += w;
    uint2 p = *(const uint2*)((const char*)h1 + (size_t)s*512 + lane*8);
    const __half2* qq=(const __half2*)&p;
    float2 f0=__half22float2(qq[0]), f1=__half22float2(qq[1]);
    acc.x += w*f0.x; acc.y += w*f0.y; acc.z += w*f1.x; acc.w += w*f1.y;
  }
  float dinv = 1.f/(wsum + 1e-16f);
  const float4 bv = *(const float4*)(bias1 + lane*4);
  float4 o;
  o.x = acc.x*dinv + bv.x;
  o.y = acc.y*dinv + bv.y;
  o.z = acc.z*dinv + bv.z;
  o.w = acc.w*dinv + bv.w;
  o.x = o.x > 0.f ? o.x : __expf(o.x)-1.f;
  o.y = o.y > 0.f ? o.y : __expf(o.y)-1.f;
  o.z = o.z > 0.f ? o.z : __expf(o.z)-1.f;
  o.w = o.w > 0.f ? o.w : __expf(o.w)-1.f;
  f16x4 ov = { (_Float16)o.x, (_Float16)o.y, (_Float16)o.z, (_Float16)o.w };
  *(f16x4*)(h2f + (size_t)wave*256 + lane*4) = ov;
}

// ---------------- GEMM2 (MFMA): hb = h2f @ W2 [N,256]@[256,16], + a_src2/a_dst2 ----------------
__global__ __launch_bounds__(256) void k_gemm2(const _Float16* __restrict__ h2f,
    const _Float16* __restrict__ W2t, const float* __restrict__ as2, const float* __restrict__ ad2,
    float* __restrict__ hb, float* __restrict__ a_src2, float* __restrict__ a_dst2, int N)
{
  int t = threadIdx.x, wv = t>>6, lane = t&63;
  int col = lane&15, q = lane>>4;
  int n0 = blockIdx.x*64 + wv*16;
  int am = n0 + col; if (am > N-1) am = N-1;

  const _Float16* arow = h2f + (size_t)am*256 + q*8;
  const _Float16* brow = W2t + (size_t)col*256 + q*8;
  f32x4 acc = (f32x4){0.f,0.f,0.f,0.f};
  #pragma unroll
  for (int ks=0; ks<8; ++ks){
    f16x8 a = *(const f16x8*)(arow + ks*32);
    f16x8 b = *(const f16x8*)(brow + ks*32);
    acc = __builtin_amdgcn_mfma_f32_16x16x32_f16(a, b, acc, 0,0,0);
  }

  float vs = as2[col], vd = ad2[col];
  #pragma unroll
  for (int r=0; r<4; ++r){
    int n = n0 + q*4 + r;
    float v = acc[r];
    float pa = v*vs, pd = v*vd;
    #pragma unroll
    for (int msk=8; msk>=1; msk>>=1){ pa += __shfl_xor(pa,msk); pd += __shfl_xor(pd,msk); }
    if (n < N){
      hb[(size_t)n*16 + col] = v;
      if (col==0){ a_src2[n] = pa; a_dst2[n] = pd; }
    }
  }
}

// ---------------- Layer-2 aggregation: wave per dst, 4 edge-groups x 16 ch ----------------
__global__ __launch_bounds__(256) void k_agg2(const float* __restrict__ hb,
    const float* __restrict__ a_src2, const float* __restrict__ a_dst2,
    const int* __restrict__ rowptr, const int* __restrict__ csr_src,
    const float* __restrict__ bias2, float* __restrict__ out, int N)
{
  int wave = (blockIdx.x*blockDim.x + threadIdx.x) >> 6;
  if (wave >= N) return;
  int lane = threadIdx.x & 63;
  int eg   = lane >> 4;
  int ch   = lane & 15;
  float ad = a_dst2[wave];
  int beg = rowptr[wave], end = rowptr[wave+1];
  float acc = 0.f, wsum = 0.f;
  int i = beg + eg;
  for (; i+4 < end; i+=8){
    int s0 = csr_src[i], s1 = csr_src[i+4];
    float e0 = a_src2[s0], e1 = a_src2[s1];
    float h0 = hb[(size_t)s0*16 + ch], h1v = hb[(size_t)s1*16 + ch];
    float w0 = __expf(lrelu(e0 + ad)), w1 = __expf(lrelu(e1 + ad));
    wsum += w0 + w1;
    acc += w0*h0 + w1*h1v;
  }
  for (; i<end; i+=4){
    int s = csr_src[i];
    float w = __expf(lrelu(a_src2[s] + ad));
    wsum += w;
    acc += w * hb[(size_t)s*16 + ch];
  }
  acc  += __shfl_xor(acc, 16);  acc  += __shfl_xor(acc, 32);
  wsum += __shfl_xor(wsum, 16); wsum += __shfl_xor(wsum, 32);
  if (eg == 0)
    out[(size_t)wave*16 + ch] = acc/(wsum + 1e-16f) + bias2[ch];
}

extern "C" void kernel_launch(void* const* d_in, const int* in_sizes, int n_in,
                              void* d_out, int out_size, void* d_ws, size_t ws_size,
                              hipStream_t stream)
{
  const float* x   = (const float*)d_in[0];
  const int*   ei  = (const int*)  d_in[1];
  const float* W1  = (const float*)d_in[2];
  const float* as1 = (const float*)d_in[3];
  const float* ad1 = (const float*)d_in[4];
  const float* b1  = (const float*)d_in[5];
  const float* W2  = (const float*)d_in[6];
  const float* as2 = (const float*)d_in[7];
  const float* ad2 = (const float*)d_in[8];
  const float* b2  = (const float*)d_in[9];
  float* out = (float*)d_out;

  const int N    = in_sizes[0] / 128;       // 50000
  const int E    = in_sizes[1] / 2;         // 800000
  const int Etot = E + N;
  const int* srcv = ei;
  const int* dstv = ei + E;
  const int chunk = (Etot + NB - 1) / NB;

  char* p = (char*)d_ws;
  auto alloc = [&](size_t bytes)->void* {
    void* r = (void*)p;
    p += (bytes + 255) & ~((size_t)255);
    return r;
  };
  _Float16* h1   = (_Float16*)alloc((size_t)N*256*sizeof(_Float16));
  _Float16* W1t  = (_Float16*)alloc((size_t)256*128*sizeof(_Float16));
  _Float16* h2f  = (_Float16*)alloc((size_t)N*256*sizeof(_Float16));
  _Float16* W2t  = (_Float16*)alloc((size_t)16*256*sizeof(_Float16));
  float* a_src1  = (float*)alloc((size_t)N*8*sizeof(float));
  float* a_dst1  = (float*)alloc((size_t)N*8*sizeof(float));
  float* hb      = (float*)alloc((size_t)N*16*sizeof(float));
  float* a_src2  = (float*)alloc((size_t)N*sizeof(float));
  float* a_dst2  = (float*)alloc((size_t)N*sizeof(float));
  int*   deg     = (int*)alloc((size_t)N*sizeof(int));
  int*   rowptr  = (int*)alloc((size_t)(N+1)*sizeof(int));
  int*   bsum    = (int*)alloc(256*sizeof(int));
  int*   partial = (int*)alloc((size_t)NB*NBINS*sizeof(int));
  int*   csr_src = (int*)alloc((size_t)Etot*sizeof(int));

  // --- CSR build (no global atomics) ---
  k_hist2<<<dim3(NB), dim3(256), 0, stream>>>(dstv, partial, E, Etot, chunk);
  k_scanA<<<dim3((NBINS+255)/256), dim3(256), 0, stream>>>(partial, deg, NBINS);
  int B = (N + 1023)/1024;
  k_scan1<<<dim3(B), dim3(256), 0, stream>>>(deg, rowptr, bsum, N);
  k_scan2<<<dim3(1), dim3(256), 0, stream>>>(bsum, B);
  k_scan3<<<dim3((N + 1 + 255)/256), dim3(256), 0, stream>>>(rowptr, bsum, N, Etot);
  k_scatter2<<<dim3(NB), dim3(256), 0, stream>>>(srcv, dstv, rowptr, partial, csr_src, E, Etot, chunk);

  // --- weight prep ---
  k_wprep<<<dim3(129), dim3(256), 0, stream>>>(W1, W1t, W2, W2t);

  // --- Layer 1 ---
  k_gemm1<<<dim3((N + 63)/64), dim3(256), 0, stream>>>(x, W1t, as1, ad1, h1, a_src1, a_dst1, N);
  k_agg1<<<dim3((N + 3)/4), dim3(256), 0, stream>>>((const __half*)h1, a_src1, a_dst1, rowptr, csr_src, b1, h2f, N);

  // --- Layer 2 ---
  k_gemm2<<<dim3((N + 63)/64), dim3(256), 0, stream>>>(h2f, W2t, as2, ad2, hb, a_src2, a_dst2, N);
  k_agg2<<<dim3((N + 3)/4), dim3(256), 0, stream>>>(hb, a_src2, a_dst2, rowptr, csr_src, b2, out, N);
}

// Round 6
// 300.255 us; speedup vs baseline: 1.1366x; 1.1366x over previous
//
#include <hip/hip_runtime.h>
#include <hip/hip_fp16.h>
#include <math.h>

// 2-layer GAT. N=50000, E=800000 (+N self loops), F=128, H=8, C=32, NCLS=16.
// R6: kernel count 12 -> 7 (theory: ~10us/dispatch serialization gaps + the R5
// 64-block CSR kernels hiding just under agg1 in the top-5).
//   k_histW   : packed 2xu16 LDS histogram, ONE edge pass (carry-safe: chunk<65536)
//               + weight prep fused (blocks 64..192)
//   k_scanAB  : per-bin sum of 64 u16 partials (u64 loads) + in-place block-prefix
//               writeback + LDS block scan -> rowptr(partial) + bsum
//   k_scatter3: packed u16 LDS cursors (50KB), redundant 49-entry bsum prefix per
//               block, direct deterministic placement (fuses scan2+scan3+scatter)
//   k_gemm1   : MFMA as before; first 49 blocks also finalize rowptr (+= bsum
//               prefix, rowptr[N]=Etot) -- CSR-independent, precedes agg1
//   k_agg1 / k_gemm2 / k_agg2: unchanged from R4/R5.

#define NB    64          // histogram/scatter blocks; chunk = ceil(850000/64) = 13282 < 65536
#define NBINS 50000
#define NW    25000       // packed u32 words (2 bins each)

typedef _Float16 f16x8 __attribute__((ext_vector_type(8)));
typedef _Float16 f16x4 __attribute__((ext_vector_type(4)));
typedef float    f32x4 __attribute__((ext_vector_type(4)));

__device__ __forceinline__ float lrelu(float v){ return v > 0.f ? v : 0.2f*v; }

// ---------------- hist (packed u16) + weight prep ----------------
__global__ __launch_bounds__(256) void k_histW(const int* __restrict__ dstv,
    unsigned int* __restrict__ partial, int E, int Etot, int chunk,
    const float* __restrict__ W1, _Float16* __restrict__ W1t,
    const float* __restrict__ W2, _Float16* __restrict__ W2t)
{
  int b = blockIdx.x, t = threadIdx.x;
  if (b >= NB){
    int b2 = b - NB;
    if (b2 < 128){
      W1t[t*128 + b2] = (_Float16)W1[b2*256 + t];
    } else {
      for (int i=t; i<4096; i+=256){ int k=i&255, j=i>>8; W2t[j*256+k] = (_Float16)W2[k*16+j]; }
    }
    return;
  }
  __shared__ unsigned int cnt[NW];
  for (int i=t; i<NW; i+=256) cnt[i] = 0u;
  __syncthreads();
  int e0 = b*chunk, e1 = e0+chunk; if (e1 > Etot) e1 = Etot;
  int e = e0 + t;
  for (; e + 768 < e1; e += 1024){
    int ea=e, eb=e+256, ec=e+512, ed=e+768;
    int d0 = (ea<E)?dstv[ea]:(ea-E);
    int d1 = (eb<E)?dstv[eb]:(eb-E);
    int d2 = (ec<E)?dstv[ec]:(ec-E);
    int d3 = (ed<E)?dstv[ed]:(ed-E);
    atomicAdd(&cnt[d0>>1], (d0&1)?65536u:1u);
    atomicAdd(&cnt[d1>>1], (d1&1)?65536u:1u);
    atomicAdd(&cnt[d2>>1], (d2&1)?65536u:1u);
    atomicAdd(&cnt[d3>>1], (d3&1)?65536u:1u);
  }
  for (; e < e1; e += 256){
    int d = (e<E)?dstv[e]:(e-E);
    atomicAdd(&cnt[d>>1], (d&1)?65536u:1u);
  }
  __syncthreads();
  unsigned int* dp = partial + (size_t)b*NW;
  for (int i=t; i<NW; i+=256) dp[i] = cnt[i];
}

// ---------------- scanA + scan1 fused ----------------
// partial[b] viewed as 12500 u64 (4 bins each). Thread owns 4 bins: sums 64
// block-partials, writes back exclusive per-block prefixes in place, then LDS
// block scan -> rowptr (block-local prefix) + bsum[blk].
__global__ __launch_bounds__(256) void k_scanAB(unsigned long long* __restrict__ partial,
    int* __restrict__ rowptr, int* __restrict__ bsum, int N)
{
  __shared__ int lds[256];
  int t = threadIdx.x, blk = blockIdx.x;
  int base = blk*1024 + t*4;
  int r0=0, r1=0, r2=0, r3=0;
  if (base < N){
    unsigned long long* P = partial + (base >> 2);
    #pragma unroll 8
    for (int b=0; b<NB; ++b){
      unsigned long long v = P[(size_t)b*12500];
      unsigned long long pref =  (unsigned long long)(r0 & 0xffff)
        | ((unsigned long long)(r1 & 0xffff) << 16)
        | ((unsigned long long)(r2 & 0xffff) << 32)
        | ((unsigned long long)(r3 & 0xffff) << 48);
      P[(size_t)b*12500] = pref;
      r0 += (int)( v        & 0xffff);
      r1 += (int)((v >> 16) & 0xffff);
      r2 += (int)((v >> 32) & 0xffff);
      r3 += (int)((v >> 48) & 0xffff);
    }
  }
  int tot = r0+r1+r2+r3;
  lds[t] = tot; __syncthreads();
  for (int off=1; off<256; off<<=1){
    int add = (t>=off)?lds[t-off]:0;
    __syncthreads();
    lds[t] += add;
    __syncthreads();
  }
  int excl = lds[t] - tot;
  if (t==255) bsum[blk] = lds[t];
  int run = excl;
  if (base+0<N){ rowptr[base+0]=run; run+=r0; }
  if (base+1<N){ rowptr[base+1]=run; run+=r1; }
  if (base+2<N){ rowptr[base+2]=run; run+=r2; }
  if (base+3<N){ rowptr[base+3]=run; }
}

// ---------------- scatter (fuses scan2+scan3 redundantly per block) ----------------
__global__ __launch_bounds__(256) void k_scatter3(const int* __restrict__ srcv,
    const int* __restrict__ dstv, const int* __restrict__ rowptr,
    const unsigned short* __restrict__ pu, const int* __restrict__ bsum,
    int* __restrict__ csr_src, int E, int Etot, int chunk, int SB)
{
  __shared__ unsigned int cur[NW];
  __shared__ int bpre[64];
  int b = blockIdx.x, t = threadIdx.x;
  for (int i=t; i<NW; i+=256) cur[i] = 0u;
  if (t==0){ int run=0; for (int j=0;j<SB;++j){ bpre[j]=run; run+=bsum[j]; } }
  __syncthreads();
  const unsigned short* pb = pu + (size_t)b*NBINS;
  int e0 = b*chunk, e1 = e0+chunk; if (e1 > Etot) e1 = Etot;
  int e = e0 + t;
  for (; e + 768 < e1; e += 1024){
    int ea=e, eb=e+256, ec=e+512, ed=e+768;
    int d0,s0,d1,s1,d2,s2,d3,s3;
    if (ea<E){ d0=dstv[ea]; s0=srcv[ea]; } else { d0=ea-E; s0=d0; }
    if (eb<E){ d1=dstv[eb]; s1=srcv[eb]; } else { d1=eb-E; s1=d1; }
    if (ec<E){ d2=dstv[ec]; s2=srcv[ec]; } else { d2=ec-E; s2=d2; }
    if (ed<E){ d3=dstv[ed]; s3=srcv[ed]; } else { d3=ed-E; s3=d3; }
    int base0 = rowptr[d0] + bpre[d0>>10] + (int)pb[d0];
    int base1 = rowptr[d1] + bpre[d1>>10] + (int)pb[d1];
    int base2 = rowptr[d2] + bpre[d2>>10] + (int)pb[d2];
    int base3 = rowptr[d3] + bpre[d3>>10] + (int)pb[d3];
    unsigned int o0 = atomicAdd(&cur[d0>>1], (d0&1)?65536u:1u);
    csr_src[base0 + ((d0&1)?(int)(o0>>16):(int)(o0&0xffff))] = s0;
    unsigned int o1 = atomicAdd(&cur[d1>>1], (d1&1)?65536u:1u);
    csr_src[base1 + ((d1&1)?(int)(o1>>16):(int)(o1&0xffff))] = s1;
    unsigned int o2 = atomicAdd(&cur[d2>>1], (d2&1)?65536u:1u);
    csr_src[base2 + ((d2&1)?(int)(o2>>16):(int)(o2&0xffff))] = s2;
    unsigned int o3 = atomicAdd(&cur[d3>>1], (d3&1)?65536u:1u);
    csr_src[base3 + ((d3&1)?(int)(o3>>16):(int)(o3&0xffff))] = s3;
  }
  for (; e < e1; e += 256){
    int d,s;
    if (e<E){ d=dstv[e]; s=srcv[e]; } else { d=e-E; s=d; }
    int base = rowptr[d] + bpre[d>>10] + (int)pb[d];
    unsigned int o = atomicAdd(&cur[d>>1], (d&1)?65536u:1u);
    csr_src[base + ((d&1)?(int)(o>>16):(int)(o&0xffff))] = s;
  }
}

// ---------------- GEMM1 (MFMA) + rowptr finalize in blocks 0..SB-1 ----------------
__global__ __launch_bounds__(256) void k_gemm1(const float* __restrict__ x,
    const _Float16* __restrict__ W1t, const float* __restrict__ as1,
    const float* __restrict__ ad1, _Float16* __restrict__ h1,
    float* __restrict__ a_src1, float* __restrict__ a_dst1,
    int* __restrict__ rowptr, const int* __restrict__ bsum, int SB, int Etot, int N)
{
  __shared__ char smem[33792];
  _Float16* As = (_Float16*)smem;           // [64 rows][136 halves] (272 B stride)
  int t = threadIdx.x;
  int n0 = blockIdx.x*64;

  // rowptr finalize (blocks 0..SB-1): rowptr[i] += prefix(bsum); rowptr[N]=Etot
  if ((int)blockIdx.x < SB){
    int blk = blockIdx.x;
    int pref = 0;
    for (int j=0;j<blk;++j) pref += bsum[j];
    int i = blk*1024 + t*4;
    if (i+0 < N) rowptr[i+0] += pref;
    if (i+1 < N) rowptr[i+1] += pref;
    if (i+2 < N) rowptr[i+2] += pref;
    if (i+3 < N) rowptr[i+3] += pref;
    if (blk==0 && t==0) rowptr[N] = Etot;
  }

  #pragma unroll
  for (int it=0; it<8; ++it){
    int c = it*256 + t;
    int row = c >> 5;
    int c4  = c & 31;
    int gr = n0 + row; if (gr > N-1) gr = N-1;
    float4 v = *(const float4*)(x + (size_t)gr*128 + c4*4);
    _Float16* dp = As + row*136 + c4*4;
    dp[0]=(_Float16)v.x; dp[1]=(_Float16)v.y; dp[2]=(_Float16)v.z; dp[3]=(_Float16)v.w;
  }
  __syncthreads();

  int wv = t>>6, lane = t&63;
  int m = lane&15, q = lane>>4;
  int r0w = wv*16;

  f16x8 afr[4];
  #pragma unroll
  for (int ks=0; ks<4; ++ks)
    afr[ks] = *(const f16x8*)((const char*)As + (r0w+m)*272 + ks*64 + q*16);

  f32x4 acc[16];
  #pragma unroll
  for (int ct=0; ct<16; ++ct) acc[ct] = (f32x4){0.f,0.f,0.f,0.f};

  const char* bbase = (const char*)W1t;
  #pragma unroll
  for (int ct=0; ct<16; ++ct){
    const char* bp = bbase + (ct*16 + m)*256 + q*16;
    f16x8 b0 = *(const f16x8*)(bp);
    f16x8 b1 = *(const f16x8*)(bp+64);
    f16x8 b2 = *(const f16x8*)(bp+128);
    f16x8 b3 = *(const f16x8*)(bp+192);
    acc[ct] = __builtin_amdgcn_mfma_f32_16x16x32_f16(afr[0], b0, acc[ct],0,0,0);
    acc[ct] = __builtin_amdgcn_mfma_f32_16x16x32_f16(afr[1], b1, acc[ct],0,0,0);
    acc[ct] = __builtin_amdgcn_mfma_f32_16x16x32_f16(afr[2], b2, acc[ct],0,0,0);
    acc[ct] = __builtin_amdgcn_mfma_f32_16x16x32_f16(afr[3], b3, acc[ct],0,0,0);
  }
  __syncthreads();

  _Float16* Hs = (_Float16*)smem;           // [64][264] halves, 528B stride
  #pragma unroll
  for (int ct=0; ct<16; ++ct){
    #pragma unroll
    for (int r=0; r<4; ++r)
      Hs[(size_t)(r0w + q*4 + r)*264 + ct*16 + m] = (_Float16)acc[ct][r];
  }
  __syncthreads();

  for (int r=0; r<16; ++r){
    int grow = n0 + r0w + r;
    if (grow < N){
      uint2 v = *(const uint2*)((const char*)Hs + (size_t)(r0w+r)*528 + lane*8);
      *(uint2*)((char*)h1 + (size_t)grow*512 + lane*8) = v;
    }
  }

  #pragma unroll
  for (int p=t; p<512; p+=256){
    int row = p>>3, hd = p&7;
    int grow = n0 + row;
    if (grow < N){
      const _Float16* hr = Hs + (size_t)row*264 + hd*32;
      float sa=0.f, sd=0.f;
      #pragma unroll
      for (int c=0; c<32; ++c){
        float hv = (float)hr[c];
        sa += hv * as1[hd*32+c];
        sd += hv * ad1[hd*32+c];
      }
      a_src1[(size_t)grow*8+hd] = sa;
      a_dst1[(size_t)grow*8+hd] = sd;
    }
  }
}

// ---------------- Layer-1 aggregation: wave per dst node, x8/x4/x1 unrolled ----------------
__global__ __launch_bounds__(256) void k_agg1(const __half* __restrict__ h1,
    const float* __restrict__ a_src1, const float* __restrict__ a_dst1,
    const int* __restrict__ rowptr, const int* __restrict__ csr_src,
    const float* __restrict__ bias1, _Float16* __restrict__ h2f, int N)
{
  int wave = (blockIdx.x*blockDim.x + threadIdx.x) >> 6;
  if (wave >= N) return;
  int lane = threadIdx.x & 63;
  int head = lane >> 3;
  float ad = a_dst1[(size_t)wave*8 + head];
  int beg = rowptr[wave], end = rowptr[wave+1];
  float4 acc = make_float4(0.f,0.f,0.f,0.f);
  float wsum = 0.f;
  int i = beg;
  for (; i+8 <= end; i+=8){
    int s[8]; float e[8]; uint2 p[8];
    #pragma unroll
    for (int j=0;j<8;++j) s[j]=csr_src[i+j];
    #pragma unroll
    for (int j=0;j<8;++j){
      e[j]=a_src1[(size_t)s[j]*8+head];
      p[j]=*(const uint2*)((const char*)h1 + (size_t)s[j]*512 + lane*8);
    }
    #pragma unroll
    for (int j=0;j<8;++j){
      float w=__expf(lrelu(e[j]+ad));
      wsum += w;
      const __half2* qq=(const __half2*)&p[j];
      float2 f0=__half22float2(qq[0]), f1=__half22float2(qq[1]);
      acc.x += w*f0.x; acc.y += w*f0.y; acc.z += w*f1.x; acc.w += w*f1.y;
    }
  }
  for (; i+4 <= end; i+=4){
    int s[4]; float e[4]; uint2 p[4];
    #pragma unroll
    for (int j=0;j<4;++j) s[j]=csr_src[i+j];
    #pragma unroll
    for (int j=0;j<4;++j){
      e[j]=a_src1[(size_t)s[j]*8+head];
      p[j]=*(const uint2*)((const char*)h1 + (size_t)s[j]*512 + lane*8);
    }
    #pragma unroll
    for (int j=0;j<4;++j){
      float w=__expf(lrelu(e[j]+ad));
      wsum += w;
      const __half2* qq=(const __half2*)&p[j];
      float2 f0=__half22float2(qq[0]), f1=__half22float2(qq[1]);
      acc.x += w*f0.x; acc.y += w*f0.y; acc.z += w*f1.x; acc.w += w*f1.y;
    }
  }
  for (; i<end; ++i){
    int s = csr_src[i];
    float w = __expf(lrelu(a_src1[(size_t)s*8+head] + ad));
    wsum += w;
    uint2 p = *(const uint2*)((const char*)h1 + (size_t)s*512 + lane*8);
    const __half2* qq=(const __half2*)&p;
    float2 f0=__half22float2(qq[0]), f1=__half22float2(qq[1]);
    acc.x += w*f0.x; acc.y += w*f0.y; acc.z += w*f1.x; acc.w += w*f1.y;
  }
  float dinv = 1.f/(wsum + 1e-16f);
  const float4 bv = *(const float4*)(bias1 + lane*4);
  float4 o;
  o.x = acc.x*dinv + bv.x;
  o.y = acc.y*dinv + bv.y;
  o.z = acc.z*dinv + bv.z;
  o.w = acc.w*dinv + bv.w;
  o.x = o.x > 0.f ? o.x : __expf(o.x)-1.f;
  o.y = o.y > 0.f ? o.y : __expf(o.y)-1.f;
  o.z = o.z > 0.f ? o.z : __expf(o.z)-1.f;
  o.w = o.w > 0.f ? o.w : __expf(o.w)-1.f;
  f16x4 ov = { (_Float16)o.x, (_Float16)o.y, (_Float16)o.z, (_Float16)o.w };
  *(f16x4*)(h2f + (size_t)wave*256 + lane*4) = ov;
}

// ---------------- GEMM2 (MFMA): hb = h2f @ W2 [N,256]@[256,16], + a_src2/a_dst2 ----------------
__global__ __launch_bounds__(256) void k_gemm2(const _Float16* __restrict__ h2f,
    const _Float16* __restrict__ W2t, const float* __restrict__ as2, const float* __restrict__ ad2,
    float* __restrict__ hb, float* __restrict__ a_src2, float* __restrict__ a_dst2, int N)
{
  int t = threadIdx.x, wv = t>>6, lane = t&63;
  int col = lane&15, q = lane>>4;
  int n0 = blockIdx.x*64 + wv*16;
  int am = n0 + col; if (am > N-1) am = N-1;

  const _Float16* arow = h2f + (size_t)am*256 + q*8;
  const _Float16* brow = W2t + (size_t)col*256 + q*8;
  f32x4 acc = (f32x4){0.f,0.f,0.f,0.f};
  #pragma unroll
  for (int ks=0; ks<8; ++ks){
    f16x8 a = *(const f16x8*)(arow + ks*32);
    f16x8 b = *(const f16x8*)(brow + ks*32);
    acc = __builtin_amdgcn_mfma_f32_16x16x32_f16(a, b, acc, 0,0,0);
  }

  float vs = as2[col], vd = ad2[col];
  #pragma unroll
  for (int r=0; r<4; ++r){
    int n = n0 + q*4 + r;
    float v = acc[r];
    float pa = v*vs, pd = v*vd;
    #pragma unroll
    for (int msk=8; msk>=1; msk>>=1){ pa += __shfl_xor(pa,msk); pd += __shfl_xor(pd,msk); }
    if (n < N){
      hb[(size_t)n*16 + col] = v;
      if (col==0){ a_src2[n] = pa; a_dst2[n] = pd; }
    }
  }
}

// ---------------- Layer-2 aggregation: wave per dst, 4 edge-groups x 16 ch ----------------
__global__ __launch_bounds__(256) void k_agg2(const float* __restrict__ hb,
    const float* __restrict__ a_src2, const float* __restrict__ a_dst2,
    const int* __restrict__ rowptr, const int* __restrict__ csr_src,
    const float* __restrict__ bias2, float* __restrict__ out, int N)
{
  int wave = (blockIdx.x*blockDim.x + threadIdx.x) >> 6;
  if (wave >= N) return;
  int lane = threadIdx.x & 63;
  int eg   = lane >> 4;
  int ch   = lane & 15;
  float ad = a_dst2[wave];
  int beg = rowptr[wave], end = rowptr[wave+1];
  float acc = 0.f, wsum = 0.f;
  int i = beg + eg;
  for (; i+4 < end; i+=8){
    int s0 = csr_src[i], s1 = csr_src[i+4];
    float e0 = a_src2[s0], e1 = a_src2[s1];
    float h0 = hb[(size_t)s0*16 + ch], h1v = hb[(size_t)s1*16 + ch];
    float w0 = __expf(lrelu(e0 + ad)), w1 = __expf(lrelu(e1 + ad));
    wsum += w0 + w1;
    acc += w0*h0 + w1*h1v;
  }
  for (; i<end; i+=4){
    int s = csr_src[i];
    float w = __expf(lrelu(a_src2[s] + ad));
    wsum += w;
    acc += w * hb[(size_t)s*16 + ch];
  }
  acc  += __shfl_xor(acc, 16);  acc  += __shfl_xor(acc, 32);
  wsum += __shfl_xor(wsum, 16); wsum += __shfl_xor(wsum, 32);
  if (eg == 0)
    out[(size_t)wave*16 + ch] = acc/(wsum + 1e-16f) + bias2[ch];
}

extern "C" void kernel_launch(void* const* d_in, const int* in_sizes, int n_in,
                              void* d_out, int out_size, void* d_ws, size_t ws_size,
                              hipStream_t stream)
{
  const float* x   = (const float*)d_in[0];
  const int*   ei  = (const int*)  d_in[1];
  const float* W1  = (const float*)d_in[2];
  const float* as1 = (const float*)d_in[3];
  const float* ad1 = (const float*)d_in[4];
  const float* b1  = (const float*)d_in[5];
  const float* W2  = (const float*)d_in[6];
  const float* as2 = (const float*)d_in[7];
  const float* ad2 = (const float*)d_in[8];
  const float* b2  = (const float*)d_in[9];
  float* out = (float*)d_out;

  const int N    = in_sizes[0] / 128;       // 50000
  const int E    = in_sizes[1] / 2;         // 800000
  const int Etot = E + N;
  const int* srcv = ei;
  const int* dstv = ei + E;
  const int chunk = (Etot + NB - 1) / NB;   // 13282 < 65536 (u16-field safe)
  const int SB    = (N + 1023) / 1024;      // 49 scan blocks

  char* p = (char*)d_ws;
  auto alloc = [&](size_t bytes)->void* {
    void* r = (void*)p;
    p += (bytes + 255) & ~((size_t)255);
    return r;
  };
  _Float16* h1   = (_Float16*)alloc((size_t)N*256*sizeof(_Float16));
  _Float16* W1t  = (_Float16*)alloc((size_t)256*128*sizeof(_Float16));
  _Float16* h2f  = (_Float16*)alloc((size_t)N*256*sizeof(_Float16));
  _Float16* W2t  = (_Float16*)alloc((size_t)16*256*sizeof(_Float16));
  float* a_src1  = (float*)alloc((size_t)N*8*sizeof(float));
  float* a_dst1  = (float*)alloc((size_t)N*8*sizeof(float));
  float* hb      = (float*)alloc((size_t)N*16*sizeof(float));
  float* a_src2  = (float*)alloc((size_t)N*sizeof(float));
  float* a_dst2  = (float*)alloc((size_t)N*sizeof(float));
  int*   rowptr  = (int*)alloc((size_t)(N+1)*sizeof(int));
  int*   bsum    = (int*)alloc(256*sizeof(int));
  unsigned int* partial = (unsigned int*)alloc((size_t)NB*NW*sizeof(unsigned int));
  int*   csr_src = (int*)alloc((size_t)Etot*sizeof(int));

  // 1. histogram (packed u16) + weight prep
  k_histW<<<dim3(NB+129), dim3(256), 0, stream>>>(dstv, partial, E, Etot, chunk,
                                                  W1, W1t, W2, W2t);
  // 2. per-bin partial prefix + block-local rowptr + bsum
  k_scanAB<<<dim3(SB), dim3(256), 0, stream>>>((unsigned long long*)partial, rowptr, bsum, N);
  // 3. deterministic scatter (bsum prefix computed redundantly per block)
  k_scatter3<<<dim3(NB), dim3(256), 0, stream>>>(srcv, dstv, rowptr,
      (const unsigned short*)partial, bsum, csr_src, E, Etot, chunk, SB);
  // 4. GEMM1 (also finalizes rowptr for agg kernels)
  k_gemm1<<<dim3((N + 63)/64), dim3(256), 0, stream>>>(x, W1t, as1, ad1, h1,
      a_src1, a_dst1, rowptr, bsum, SB, Etot, N);
  // 5-7. agg1, gemm2, agg2
  k_agg1<<<dim3((N + 3)/4), dim3(256), 0, stream>>>((const __half*)h1, a_src1, a_dst1,
      rowptr, csr_src, b1, h2f, N);
  k_gemm2<<<dim3((N + 63)/64), dim3(256), 0, stream>>>(h2f, W2t, as2, ad2, hb, a_src2, a_dst2, N);
  k_agg2<<<dim3((N + 3)/4), dim3(256), 0, stream>>>(hb, a_src2, a_dst2, rowptr, csr_src, b2, out, N);
}